// Round 5
// baseline (547.573 us; speedup 1.0000x reference)
//
#include <hip/hip_runtime.h>

// MEASUREMENT ROUND.
// Kernel 1 (unchanged from R4): out[row] = rowsum(x) * sum(coeffs). Correctness.
// Kernel 2 (probe): identical access pattern but sweeps x PROBE_REPEATS times,
// writing per-wave garbage to ws. Sized to exceed the 161 us harness fills so
// it surfaces in the rocprof top-5 WITH counters (dur/FETCH/VALU/occupancy).

#define WAVES_PER_BLOCK 4
#define NUM_BLOCKS 2048
#define PROBE_REPEATS 5

__global__ __launch_bounds__(256) void spline_rowsum_kernel(
    const float* __restrict__ x,
    const float* __restrict__ coeffs,
    float* __restrict__ out,
    int nrows) {
  const int lane = threadIdx.x & 63;
  const int w = blockIdx.x * WAVES_PER_BLOCK + (threadIdx.x >> 6);
  const int total_waves = NUM_BLOCKS * WAVES_PER_BLOCK;  // 8192

  float cs = 0.0f;
#pragma unroll
  for (int k = 0; k < 10; ++k) cs += coeffs[k];

  const int npairs = nrows >> 1;  // 32768
  for (int p = w; p < npairs; p += total_waves) {
    const int r = p << 1;  // rows r, r+1: 8 KiB contiguous
    const float4* xa = reinterpret_cast<const float4*>(
                           x + (long long)r * 1024) + lane;
    float4 a0 = xa[0 * 64];
    float4 a1 = xa[1 * 64];
    float4 a2 = xa[2 * 64];
    float4 a3 = xa[3 * 64];
    float4 b0 = xa[4 * 64];
    float4 b1 = xa[5 * 64];
    float4 b2 = xa[6 * 64];
    float4 b3 = xa[7 * 64];

    float sa = ((a0.x + a0.y) + (a0.z + a0.w)) + ((a1.x + a1.y) + (a1.z + a1.w))
             + ((a2.x + a2.y) + (a2.z + a2.w)) + ((a3.x + a3.y) + (a3.z + a3.w));
    float sb = ((b0.x + b0.y) + (b0.z + b0.w)) + ((b1.x + b1.y) + (b1.z + b1.w))
             + ((b2.x + b2.y) + (b2.z + b2.w)) + ((b3.x + b3.y) + (b3.z + b3.w));

#pragma unroll
    for (int off = 32; off > 0; off >>= 1) {
      sa += __shfl_down(sa, off, 64);
      sb += __shfl_down(sb, off, 64);
    }
    if (lane == 0) {
      out[r] = sa * cs;
      out[r + 1] = sb * cs;
    }
  }
}

// Probe: same pattern, 5 full sweeps of x. Pair index rotated per sweep so the
// compiler cannot hoist/CSE the loads across repeats. Result written to ws.
__global__ __launch_bounds__(256) void probe_sweep_kernel(
    const float* __restrict__ x,
    float* __restrict__ ws) {
  const int lane = threadIdx.x & 63;
  const int w = blockIdx.x * WAVES_PER_BLOCK + (threadIdx.x >> 6);
  const int total_waves = NUM_BLOCKS * WAVES_PER_BLOCK;  // 8192

  float acc = 0.0f;
  for (int rep = 0; rep < PROBE_REPEATS; ++rep) {
    for (int p = w; p < 32768; p += total_waves) {
      const int q = (p + rep * 4096) & 32767;  // rotated full sweep
      const float4* xa = reinterpret_cast<const float4*>(
                             x + (long long)q * 2048) + lane;
      float4 a0 = xa[0 * 64];
      float4 a1 = xa[1 * 64];
      float4 a2 = xa[2 * 64];
      float4 a3 = xa[3 * 64];
      float4 b0 = xa[4 * 64];
      float4 b1 = xa[5 * 64];
      float4 b2 = xa[6 * 64];
      float4 b3 = xa[7 * 64];
      acc += ((a0.x + a0.y) + (a0.z + a0.w)) + ((a1.x + a1.y) + (a1.z + a1.w))
           + ((a2.x + a2.y) + (a2.z + a2.w)) + ((a3.x + a3.y) + (a3.z + a3.w))
           + ((b0.x + b0.y) + (b0.z + b0.w)) + ((b1.x + b1.y) + (b1.z + b1.w))
           + ((b2.x + b2.y) + (b2.z + b2.w)) + ((b3.x + b3.y) + (b3.z + b3.w));
    }
  }
#pragma unroll
  for (int off = 32; off > 0; off >>= 1) acc += __shfl_down(acc, off, 64);
  if (lane == 0) ws[w] = acc;  // prevent DCE; ws is scratch
}

extern "C" void kernel_launch(void* const* d_in, const int* in_sizes, int n_in,
                              void* d_out, int out_size, void* d_ws, size_t ws_size,
                              hipStream_t stream) {
  const float* x      = (const float*)d_in[0];   // 16*4096*1024 fp32
  const float* coeffs = (const float*)d_in[1];   // 10 fp32
  float* out          = (float*)d_out;           // 65536 fp32

  spline_rowsum_kernel<<<NUM_BLOCKS, 256, 0, stream>>>(x, coeffs, out, out_size);
  probe_sweep_kernel<<<NUM_BLOCKS, 256, 0, stream>>>(x, (float*)d_ws);
}

// Round 6
// 530.062 us; speedup vs baseline: 1.0330x; 1.0330x over previous
//
#include <hip/hip_runtime.h>

// MEASUREMENT ROUND 2.
// Kernel 1 (unchanged R4 spline): correctness + the real workload.
// Kernel 2 (probe): stream-read the ENTIRE 1 GiB d_ws (>=768 MB guaranteed
// HBM-cold, since L3 = 256 MiB). Measures pure HBM *read* bandwidth for the
// exact load shape the spline kernel uses (8 x float4 per wave-iteration,
// 8 KiB contiguous per wave-chunk). Lands top-1 in rocprof with counters.

#define WAVES_PER_BLOCK 4
#define NUM_BLOCKS 2048

__global__ __launch_bounds__(256) void spline_rowsum_kernel(
    const float* __restrict__ x,
    const float* __restrict__ coeffs,
    float* __restrict__ out,
    int nrows) {
  const int lane = threadIdx.x & 63;
  const int w = blockIdx.x * WAVES_PER_BLOCK + (threadIdx.x >> 6);
  const int total_waves = NUM_BLOCKS * WAVES_PER_BLOCK;  // 8192

  float cs = 0.0f;
#pragma unroll
  for (int k = 0; k < 10; ++k) cs += coeffs[k];

  const int npairs = nrows >> 1;  // 32768
  for (int p = w; p < npairs; p += total_waves) {
    const int r = p << 1;  // rows r, r+1: 8 KiB contiguous
    const float4* xa = reinterpret_cast<const float4*>(
                           x + (long long)r * 1024) + lane;
    float4 a0 = xa[0 * 64];
    float4 a1 = xa[1 * 64];
    float4 a2 = xa[2 * 64];
    float4 a3 = xa[3 * 64];
    float4 b0 = xa[4 * 64];
    float4 b1 = xa[5 * 64];
    float4 b2 = xa[6 * 64];
    float4 b3 = xa[7 * 64];

    float sa = ((a0.x + a0.y) + (a0.z + a0.w)) + ((a1.x + a1.y) + (a1.z + a1.w))
             + ((a2.x + a2.y) + (a2.z + a2.w)) + ((a3.x + a3.y) + (a3.z + a3.w));
    float sb = ((b0.x + b0.y) + (b0.z + b0.w)) + ((b1.x + b1.y) + (b1.z + b1.w))
             + ((b2.x + b2.y) + (b2.z + b2.w)) + ((b3.x + b3.y) + (b3.z + b3.w));

#pragma unroll
    for (int off = 32; off > 0; off >>= 1) {
      sa += __shfl_down(sa, off, 64);
      sb += __shfl_down(sb, off, 64);
    }
    if (lane == 0) {
      out[r] = sa * cs;
      out[r + 1] = sb * cs;
    }
  }
}

// Probe: stream-read all of ws (poisoned 0xAA -> tiny denormal floats, fine).
// Each wave-chunk = 8 KiB contiguous; same 8-load shape as the spline kernel.
__global__ __launch_bounds__(256) void probe_ws_read_kernel(
    const float* __restrict__ wsr,
    float* __restrict__ wsw,
    long long nchunks) {
  const int lane = threadIdx.x & 63;
  const int w = blockIdx.x * WAVES_PER_BLOCK + (threadIdx.x >> 6);
  const int total_waves = NUM_BLOCKS * WAVES_PER_BLOCK;  // 8192

  float acc = 0.0f;
  for (long long c = w; c < nchunks; c += total_waves) {
    const float4* p = reinterpret_cast<const float4*>(wsr) + c * 512 + lane;
    float4 a0 = p[0 * 64];
    float4 a1 = p[1 * 64];
    float4 a2 = p[2 * 64];
    float4 a3 = p[3 * 64];
    float4 b0 = p[4 * 64];
    float4 b1 = p[5 * 64];
    float4 b2 = p[6 * 64];
    float4 b3 = p[7 * 64];
    acc += ((a0.x + a0.y) + (a0.z + a0.w)) + ((a1.x + a1.y) + (a1.z + a1.w))
         + ((a2.x + a2.y) + (a2.z + a2.w)) + ((a3.x + a3.y) + (a3.z + a3.w))
         + ((b0.x + b0.y) + (b0.z + b0.w)) + ((b1.x + b1.y) + (b1.z + b1.w))
         + ((b2.x + b2.y) + (b2.z + b2.w)) + ((b3.x + b3.y) + (b3.z + b3.w));
  }
#pragma unroll
  for (int off = 32; off > 0; off >>= 1) acc += __shfl_down(acc, off, 64);
  if (lane == 0) wsw[w] = acc;  // after all reads; ws is scratch
}

extern "C" void kernel_launch(void* const* d_in, const int* in_sizes, int n_in,
                              void* d_out, int out_size, void* d_ws, size_t ws_size,
                              hipStream_t stream) {
  const float* x      = (const float*)d_in[0];   // 16*4096*1024 fp32
  const float* coeffs = (const float*)d_in[1];   // 10 fp32
  float* out          = (float*)d_out;           // 65536 fp32

  spline_rowsum_kernel<<<NUM_BLOCKS, 256, 0, stream>>>(x, coeffs, out, out_size);

  long long nchunks = (long long)(ws_size / 8192);  // 8 KiB chunks; ~131072 for 1 GiB
  probe_ws_read_kernel<<<NUM_BLOCKS, 256, 0, stream>>>(
      (const float*)d_ws, (float*)d_ws, nchunks);
}